// Round 5
// baseline (244.337 us; speedup 1.0000x reference)
//
#include <hip/hip_runtime.h>

#define GRIDW 48
#define NNODES 147456
#define NTILES 2304   // NNODES/64
#define GB 512        // persistent GEMM grid
#define NSH 8         // stat shadow copies (XCD-indexed)
#define SHS 128       // shadow stride (floats)

typedef __attribute__((ext_vector_type(8))) short short8;
typedef __attribute__((ext_vector_type(4))) float f32x4;

__device__ inline unsigned short f2bf(float f) {
    union { float f; unsigned u; } v; v.f = f;
    unsigned r = v.u + 0x7FFFu + ((v.u >> 16) & 1u);
    return (unsigned short)(r >> 16);
}
__device__ inline float bf2f(unsigned short h) {
    union { unsigned u; float f; } v; v.u = ((unsigned)h) << 16;
    return v.f;
}
__device__ __forceinline__ f32x4 b2v(uint2 v) {
    f32x4 r;
    r.x = bf2f((unsigned short)(v.x & 0xFFFFu));
    r.y = bf2f((unsigned short)(v.x >> 16));
    r.z = bf2f((unsigned short)(v.y & 0xFFFFu));
    r.w = bf2f((unsigned short)(v.y >> 16));
    return r;
}

// ---------------------------------------------------------------------------
// prep: weights->bf16 [col][KP] (k-contig, zero-padded), padded biases,
// zero stat shadows (re-zeroed every graph replay -> atomic accum safe).
// wt2 is 176 cols: [g2(132) | w2(44)].
// ---------------------------------------------------------------------------
__global__ void prep(const float* __restrict__ w0, const float* __restrict__ b0,
                     const float* __restrict__ w1, const float* __restrict__ b1,
                     const float* __restrict__ g2, const float* __restrict__ w2,
                     const float* __restrict__ b2, const float* __restrict__ w3,
                     const float* __restrict__ b3,
                     unsigned short* __restrict__ wt0, unsigned short* __restrict__ wt1,
                     unsigned short* __restrict__ wt2, unsigned short* __restrict__ wt3,
                     float* __restrict__ biasf0, float* __restrict__ biasf1,
                     float* __restrict__ biasf2, float* __restrict__ biasf3,
                     float* __restrict__ statz) {
    int id = blockIdx.x * 256 + threadIdx.x;
    if (id < 14336) {                         // wt0: 112 cols x 128 k
        int col = id >> 7, k = id & 127;
        wt0[id] = (col < 102) ? f2bf(w0[k * 102 + col]) : (unsigned short)0;
    } else if (id < 24576) {                  // wt1: 80 x 128
        int e = id - 14336; int col = e >> 7, k = e & 127;
        wt1[e] = (col < 73 && k < 102) ? f2bf(w1[k * 73 + col]) : (unsigned short)0;
    } else if (id < 41472) {                  // wt2: 176 x 96 (g2 | w2)
        int e = id - 24576; int col = e / 96, k = e - (e / 96) * 96;
        unsigned short v = 0;
        if (k < 73) v = (col < 132) ? f2bf(g2[k * 132 + col]) : f2bf(w2[k * 44 + (col - 132)]);
        wt2[e] = v;
    } else if (id < 42496) {                  // wt3: 16 x 64
        int e = id - 41472; int col = e >> 6, k = e & 63;
        wt3[e] = (k < 44) ? f2bf(w3[k * 16 + col]) : (unsigned short)0;
    } else if (id < 42608) { int c = id - 42496; biasf0[c] = (c < 102) ? b0[c] : 0.f; }
    else if (id < 42688) { int c = id - 42608; biasf1[c] = (c < 73) ? b1[c] : 0.f; }
    else if (id < 42864) { int c = id - 42688; biasf2[c] = (c < 132) ? 0.f : b2[c - 132]; }
    else if (id < 42880) { int c = id - 42864; biasf3[c] = b3[c]; }
    else if (id < 49024) { statz[id - 42880] = 0.f; }   // 6 x 1024 stat shadows
}

// ---------------------------------------------------------------------------
// Persistent MFMA GEMM: whole-K in LDS, 64-row tiles grid-strided,
// double-buffered A with register prefetch, BN of the previous layer applied
// on the A side during LDS commit. STATS: per-block reduction -> atomicAdd
// into 8 XCD-indexed shadow copies; consumers sum shadows in prologue.
// ---------------------------------------------------------------------------
template<int K, int KP, int MP, int MOUT, int PREVM, int BNSRC,
         bool STATS, bool OUTBF, bool ABF16>
__global__ __launch_bounds__(256) void gemm_p(
    const void* __restrict__ Ain, const unsigned short* __restrict__ WT,
    const float* __restrict__ biasf,
    const float* __restrict__ q0, const float* __restrict__ q1,
    const float* __restrict__ q2, const float* __restrict__ q3,
    float invN, void* __restrict__ Yout,
    float* __restrict__ sumO, float* __restrict__ ssO)
{
    constexpr int KS = KP + 8;
    constexpr int NCF = MP / 16;
    constexpr int UPR = ABF16 ? (K / 8) : (K / 4);
    constexpr int TOT = 64 * UPR;
    constexpr int NLD = (TOT + 255) / 256;
    __shared__ __align__(16) unsigned short As[2][64 * KS];
    __shared__ __align__(16) unsigned short Bs[MP * KS];
    __shared__ float bnA[KP], bnB[KP];

    const int tid = threadIdx.x;
    const int lane = tid & 63, wv = tid >> 6, qd = lane >> 4, lc = lane & 15;

    if (BNSRC == 1) {
        if (tid < KP) {
            float a = 0.f, b = 0.f;
            if (tid < PREVM) {
                float s0 = 0.f, s1 = 0.f;
#pragma unroll
                for (int sh = 0; sh < NSH; ++sh) {
                    s0 += q0[sh * SHS + tid];
                    s1 += q1[sh * SHS + tid];
                }
                float m = s0 * invN;
                float v = s1 * invN - m * m;
                float sc = q2[tid] * rsqrtf(v + 1e-5f);
                a = sc; b = q3[tid] - m * sc;
            }
            bnA[tid] = a; bnB[tid] = b;
        }
    }
    for (int g = tid; g < MP * (KP / 8); g += 256) {
        int col = g / (KP / 8), u = g - col * (KP / 8);
        *(uint4*)&Bs[col * KS + u * 8] = *(const uint4*)&WT[(size_t)col * KP + u * 8];
    }
    if constexpr (KP > K) {
        constexpr int PADU = (KP - K) / 2;
        for (int g = tid; g < 64 * PADU; g += 256) {
            int row = g / PADU, u = g - row * PADU;
            *(unsigned*)&As[0][row * KS + K + u * 2] = 0u;
            *(unsigned*)&As[1][row * KS + K + u * 2] = 0u;
        }
    }

    float bvr[NCF];
#pragma unroll
    for (int cf = 0; cf < NCF; ++cf) bvr[cf] = biasf[cf * 16 + lc];

    float cs[NCF], cq[NCF];
    if (STATS) {
#pragma unroll
        for (int cf = 0; cf < NCF; ++cf) { cs[cf] = 0.f; cq[cf] = 0.f; }
    }

    uint4 pfb[NLD];
    float4 pff[NLD];

    int t = blockIdx.x;
#pragma unroll
    for (int i = 0; i < NLD; ++i) {
        int g = tid + 256 * i;
        if (g < TOT) {
            if constexpr (ABF16)
                pfb[i] = *(const uint4*)((const unsigned short*)Ain + (size_t)t * 64 * K + g * 8);
            else
                pff[i] = *(const float4*)((const float*)Ain + (size_t)t * 64 * K + g * 4);
        }
    }
    __syncthreads();

    int buf = 0;
    for (; t < NTILES; t += GB) {
#pragma unroll
        for (int i = 0; i < NLD; ++i) {
            int g = tid + 256 * i;
            if (g < TOT) {
                int row = g / UPR, u = g - row * UPR;
                if constexpr (ABF16) {
                    uint4 w = pfb[i];
                    if (BNSRC != 0) {
                        unsigned* wp = (unsigned*)&w;
#pragma unroll
                        for (int pp = 0; pp < 4; ++pp) {
                            int kk = u * 8 + 2 * pp;
                            float lo = bf2f((unsigned short)(wp[pp] & 0xFFFFu)) * bnA[kk] + bnB[kk];
                            float hi = bf2f((unsigned short)(wp[pp] >> 16)) * bnA[kk + 1] + bnB[kk + 1];
                            wp[pp] = (unsigned)f2bf(lo) | ((unsigned)f2bf(hi) << 16);
                        }
                    }
                    *(uint4*)&As[buf][row * KS + u * 8] = w;
                } else {
                    float4 v = pff[i];
                    if (BNSRC != 0) {
                        int kk = u * 4;
                        v.x = v.x * bnA[kk] + bnB[kk];
                        v.y = v.y * bnA[kk + 1] + bnB[kk + 1];
                        v.z = v.z * bnA[kk + 2] + bnB[kk + 2];
                        v.w = v.w * bnA[kk + 3] + bnB[kk + 3];
                    }
                    unsigned lo = (unsigned)f2bf(v.x) | ((unsigned)f2bf(v.y) << 16);
                    unsigned hi = (unsigned)f2bf(v.z) | ((unsigned)f2bf(v.w) << 16);
                    *(uint2*)&As[buf][row * KS + u * 4] = make_uint2(lo, hi);
                }
            }
        }
        int t2 = t + GB;
        if (t2 < NTILES) {
#pragma unroll
            for (int i = 0; i < NLD; ++i) {
                int g = tid + 256 * i;
                if (g < TOT) {
                    if constexpr (ABF16)
                        pfb[i] = *(const uint4*)((const unsigned short*)Ain + (size_t)t2 * 64 * K + g * 8);
                    else
                        pff[i] = *(const float4*)((const float*)Ain + (size_t)t2 * 64 * K + g * 4);
                }
            }
        }
        __syncthreads();

        f32x4 acc[NCF];
#pragma unroll
        for (int cf = 0; cf < NCF; ++cf) acc[cf] = (f32x4){0.f, 0.f, 0.f, 0.f};
#pragma unroll
        for (int kt = 0; kt < KP / 32; ++kt) {
            const int kb = kt * 32 + qd * 8;
            short8 a = *(const short8*)&As[buf][(wv * 16 + lc) * KS + kb];
#pragma unroll
            for (int cf = 0; cf < NCF; ++cf) {
                short8 b = *(const short8*)&Bs[(cf * 16 + lc) * KS + kb];
                acc[cf] = __builtin_amdgcn_mfma_f32_16x16x32_bf16(a, b, acc[cf], 0, 0, 0);
            }
        }
#pragma unroll
        for (int cf = 0; cf < NCF; ++cf) {
            const int col = cf * 16 + lc;
            const float bv = bvr[cf];
#pragma unroll
            for (int rr = 0; rr < 4; ++rr) {
                float v = acc[cf][rr] + bv;
                int row = t * 64 + wv * 16 + qd * 4 + rr;
                if (OUTBF) ((unsigned short*)Yout)[(size_t)row * MP + col] = f2bf(v);
                else       ((float*)Yout)[(size_t)row * MP + col] = v;
                if (STATS) { cs[cf] += v; cq[cf] += v * v; }
            }
        }
        buf ^= 1;
    }

    if (STATS) {
        __syncthreads();
        float* red = (float*)As;
        float* redq = red + 4 * MP;
#pragma unroll
        for (int cf = 0; cf < NCF; ++cf) {
            float s = cs[cf], qq = cq[cf];
            s += __shfl_down(s, 32, 64); s += __shfl_down(s, 16, 64);
            qq += __shfl_down(qq, 32, 64); qq += __shfl_down(qq, 16, 64);
            if (lane < 16) {
                red[wv * MP + cf * 16 + lane] = s;
                redq[wv * MP + cf * 16 + lane] = qq;
            }
        }
        __syncthreads();
        if (tid < MOUT) {
            float s = red[tid] + red[MP + tid] + red[2 * MP + tid] + red[3 * MP + tid];
            float qq = redq[tid] + redq[MP + tid] + redq[2 * MP + tid] + redq[3 * MP + tid];
            const int sh = blockIdx.x & (NSH - 1);      // XCD-indexed shadow
            atomicAdd(&sumO[sh * SHS + tid], s);
            atomicAdd(&ssO[sh * SHS + tid], qq);
        }
    }
}

// ---------------------------------------------------------------------------
// Separable GMM stencil (round 14): ALL state as named f32x4 SSA values —
// 5 x-columns x 3 Gaussians = 15 named vectors, never memory-backed (the
// r13 array version stayed in scratch: VGPR_Count=48 proved it). Flat load
// phase: all 45 t-loads + 3 residual loads issued together (max MLP), then
// pure-register compute. Math order per element identical to r13.
// ---------------------------------------------------------------------------
__global__ __launch_bounds__(256) void gmm_stencil(
    const unsigned short* __restrict__ TR, unsigned short* __restrict__ C,
    const float* __restrict__ mu, const float* __restrict__ sigma,
    float* __restrict__ sum2, float* __restrict__ ss2)
{
    __shared__ float gx[3][3], gy[3][3];   // [d][k]
    __shared__ float red[88];
    const int tid = threadIdx.x;
    if (tid < 88) red[tid] = 0.f;
    if (tid < 18) {
        int d = (tid / 3) % 3, k = tid % 3;
        bool isy = tid >= 9;
        float e = 0.5f * (float)(d - 1) + 0.5f;
        float mm = mu[k * 2 + (isy ? 1 : 0)];
        float sg = sigma[k * 2 + (isy ? 1 : 0)];
        float v = expf(-0.5f * (e - mm) * (e - mm) / (1e-15f + sg * sg));
        if (isy) gy[d][k] = v; else gx[d][k] = v;
    }
    __syncthreads();

    // flat uniform mapping, XCD-locality-preserving
    const int xcd = blockIdx.x & 7;
    const int bi  = blockIdx.x >> 3;              // 0..263
    const int b   = xcd * 8 + bi / 33;            // 8 batches per XCD slot
    const unsigned tau = (unsigned)(bi % 33) * 256u + (unsigned)tid;  // 0..8447
    const int og = (int)(tau % 11u);
    const unsigned r1 = tau / 11u;                // 0..767
    const int iy = (int)(r1 % 48u);
    const int x0 = (int)(r1 / 48u) * 3;           // 0..45 step 3
    const int c0 = og * 4;

    // hoist the 18 Gaussian coefficients LDS -> registers (static indices)
    float gxr[3][3], gyr[3][3];
#pragma unroll
    for (int d = 0; d < 3; ++d)
#pragma unroll
        for (int k = 0; k < 3; ++k) { gxr[d][k] = gx[d][k]; gyr[d][k] = gy[d][k]; }

    const int ny = 1 + (iy > 0) + (iy < GRIDW - 1);

    // y-combined column loads: named SSA vectors only.
#define LOADU(JX, U0, U1, U2)                                                  \
    {                                                                          \
        U0 = (f32x4){0.f, 0.f, 0.f, 0.f};                                      \
        U1 = (f32x4){0.f, 0.f, 0.f, 0.f};                                      \
        U2 = (f32x4){0.f, 0.f, 0.f, 0.f};                                      \
        const int jx_ = (JX);                                                  \
        if (jx_ >= 0 && jx_ < GRIDW) {                                         \
            const unsigned short* rowp_ =                                      \
                TR + (size_t)(b * 2304 + jx_ * 48) * 176;                      \
            _Pragma("unroll")                                                  \
            for (int dy = -1; dy <= 1; ++dy) {                                 \
                const int jy_ = iy + dy;                                       \
                if (jy_ < 0 || jy_ >= GRIDW) continue;                         \
                const unsigned short* np_ = rowp_ + (size_t)jy_ * 176 + c0;    \
                uint2 v0_ = *(const uint2*)(np_);                              \
                uint2 v1_ = *(const uint2*)(np_ + 44);                         \
                uint2 v2_ = *(const uint2*)(np_ + 88);                         \
                U0 += gyr[dy + 1][0] * b2v(v0_);                               \
                U1 += gyr[dy + 1][1] * b2v(v1_);                               \
                U2 += gyr[dy + 1][2] * b2v(v2_);                               \
            }                                                                  \
        }                                                                      \
    }

    f32x4 ua0, ua1, ua2, ub0, ub1, ub2, uc0, uc1, uc2, ud0, ud1, ud2, ue0, ue1, ue2;
    LOADU(x0 - 1, ua0, ua1, ua2)
    LOADU(x0,     ub0, ub1, ub2)
    LOADU(x0 + 1, uc0, uc1, uc2)
    LOADU(x0 + 2, ud0, ud1, ud2)
    LOADU(x0 + 3, ue0, ue1, ue2)
#undef LOADU

    // residual (root) loads for the 3 output nodes — issue with the above
    const int node0 = b * 2304 + (x0 + 0) * 48 + iy;
    const int node1 = b * 2304 + (x0 + 1) * 48 + iy;
    const int node2 = b * 2304 + (x0 + 2) * 48 + iy;
    uint2 rv0 = *(const uint2*)(TR + (size_t)node0 * 176 + 132 + c0);
    uint2 rv1 = *(const uint2*)(TR + (size_t)node1 * 176 + 132 + c0);
    uint2 rv2 = *(const uint2*)(TR + (size_t)node2 * 176 + 132 + c0);

    f32x4 s4 = (f32x4){0.f, 0.f, 0.f, 0.f};
    f32x4 q4 = (f32x4){0.f, 0.f, 0.f, 0.f};

#define GOUT(ST, NODE, RV, A0, A1, A2, B0, B1, B2, D0, D1, D2)                 \
    {                                                                          \
        const int ix_ = x0 + (ST);                                             \
        const int nx_ = 1 + (ix_ > 0) + (ix_ < GRIDW - 1);                     \
        const float inv_ = 1.f / (float)(nx_ * ny);                            \
        f32x4 o = (f32x4){0.f, 0.f, 0.f, 0.f};                                 \
        o += gxr[0][0] * A0 + gxr[1][0] * B0 + gxr[2][0] * D0;                 \
        o += gxr[0][1] * A1 + gxr[1][1] * B1 + gxr[2][1] * D1;                 \
        o += gxr[0][2] * A2 + gxr[1][2] * B2 + gxr[2][2] * D2;                 \
        o = o * inv_;                                                          \
        o += b2v(RV);                                                          \
        unsigned lo_ = (unsigned)f2bf(o.x) | ((unsigned)f2bf(o.y) << 16);      \
        unsigned hi_ = (unsigned)f2bf(o.z) | ((unsigned)f2bf(o.w) << 16);      \
        *(uint2*)&C[(size_t)(NODE) * 48 + c0] = make_uint2(lo_, hi_);          \
        if (og == 10)                                                          \
            *(uint2*)&C[(size_t)(NODE) * 48 + 44] = make_uint2(0u, 0u);        \
        s4 += o; q4 += o * o;                                                  \
    }

    GOUT(0, node0, rv0, ua0, ua1, ua2, ub0, ub1, ub2, uc0, uc1, uc2)
    GOUT(1, node1, rv1, ub0, ub1, ub2, uc0, uc1, uc2, ud0, ud1, ud2)
    GOUT(2, node2, rv2, uc0, uc1, uc2, ud0, ud1, ud2, ue0, ue1, ue2)
#undef GOUT

    atomicAdd(&red[c0 + 0], s4.x);
    atomicAdd(&red[c0 + 1], s4.y);
    atomicAdd(&red[c0 + 2], s4.z);
    atomicAdd(&red[c0 + 3], s4.w);
    atomicAdd(&red[44 + c0 + 0], q4.x);
    atomicAdd(&red[44 + c0 + 1], q4.y);
    atomicAdd(&red[44 + c0 + 2], q4.z);
    atomicAdd(&red[44 + c0 + 3], q4.w);
    __syncthreads();
    if (tid < 88) {
        const int sh = blockIdx.x & (NSH - 1);
        if (tid < 44) atomicAdd(&sum2[sh * SHS + tid], red[tid]);
        else          atomicAdd(&ss2[sh * SHS + tid - 44], red[tid]);
    }
}

// ---------------------------------------------------------------------------
extern "C" void kernel_launch(void* const* d_in, const int* in_sizes, int n_in,
                              void* d_out, int out_size, void* d_ws, size_t ws_size,
                              hipStream_t stream) {
    const float* x      = (const float*)d_in[0];
    const float* w0     = (const float*)d_in[3];
    const float* b0     = (const float*)d_in[4];
    const float* gamma0 = (const float*)d_in[5];
    const float* beta0  = (const float*)d_in[6];
    const float* w1     = (const float*)d_in[7];
    const float* b1     = (const float*)d_in[8];
    const float* gamma1 = (const float*)d_in[9];
    const float* beta1  = (const float*)d_in[10];
    const float* w2     = (const float*)d_in[11];
    const float* g2     = (const float*)d_in[12];
    const float* mu2    = (const float*)d_in[13];
    const float* sigma2 = (const float*)d_in[14];
    const float* b2     = (const float*)d_in[15];
    const float* gamma2 = (const float*)d_in[16];
    const float* beta2  = (const float*)d_in[17];
    const float* w3     = (const float*)d_in[18];
    const float* b3     = (const float*)d_in[19];
    float* out = (float*)d_out;

    const int N = NNODES;
    const float invN = 1.0f / (float)N;

    // [0,44N): Y1 bf16 (40N f-eq) then C bf16 48 cols (24N f-eq) — disjoint
    // [44N,132N): Y0 bf16 (56N f-eq) then TR bf16 176 cols (88N f-eq) — disjoint
    const size_t tailOff = (size_t)N * 132;
    size_t need = (tailOff + 300000) * sizeof(float);
    if (ws_size < need) return;

    float* ws = (float*)d_ws;
    unsigned short* bufY1 = (unsigned short*)ws;
    unsigned short* bufC  = (unsigned short*)ws;
    unsigned short* bufY0 = (unsigned short*)(ws + (size_t)N * 44);
    unsigned short* bufTR = bufY0;

    float* tail = ws + tailOff;
    // 6 stat arrays x 8 shadows x 128 stride = 6144 floats
    float* sum0 = tail;                 // 1024
    float* ss0  = tail + 1024;          // 1024
    float* sum1 = tail + 2048;          // 1024
    float* ss1  = tail + 3072;          // 1024
    float* sum2 = tail + 4096;          // 1024
    float* ss2  = tail + 5120;          // 1024
    float* biasf0 = tail + 6144;        // 112
    float* biasf1 = tail + 6256;        // 80
    float* biasf2 = tail + 6336;        // 176
    float* biasf3 = tail + 6512;        // 16
    unsigned short* wt0 = (unsigned short*)(tail + 6528);   // 112*128
    unsigned short* wt1 = wt0 + 14336;                      // 80*128
    unsigned short* wt2 = wt1 + 10240;                      // 176*96
    unsigned short* wt3 = wt2 + 16896;                      // 16*64

    // prep re-zeros the stat shadows each replay (graph-safe).
    prep<<<192, 256, 0, stream>>>(w0, b0, w1, b1, g2, w2, b2, w3, b3,
                                  wt0, wt1, wt2, wt3,
                                  biasf0, biasf1, biasf2, biasf3, tail);

    // L0: Y0 = x @ w0 + b0 (bf16 out, stats -> sum0/ss0 shadows)
    gemm_p<128, 128, 112, 102, 0, 0, true, true, false><<<GB, 256, 0, stream>>>(
        x, wt0, biasf0, nullptr, nullptr, nullptr, nullptr, invN, bufY0, sum0, ss0);

    // L1: Y1 = BN0(Y0) @ w1 + b1 (BN on A-side; stats -> sum1/ss1 shadows)
    gemm_p<112, 128, 80, 73, 102, 1, true, true, true><<<GB, 256, 0, stream>>>(
        bufY0, wt1, biasf1, sum0, ss0, gamma0, beta0, invN, bufY1, sum1, ss1);

    // L2: TR = BN1(Y1) @ [g2 | w2] (+[0|b2]), 176 wide
    gemm_p<80, 96, 176, 176, 73, 1, false, true, true><<<GB, 256, 0, stream>>>(
        bufY1, wt2, biasf2, sum1, ss1, gamma1, beta1, invN, bufTR, nullptr, nullptr);

    // separable stencil: C(bf16,48) = r + agg(t)/deg ; stats -> sum2/ss2 shadows
    gmm_stencil<<<2112, 256, 0, stream>>>(bufTR, bufC, mu2, sigma2, sum2, ss2);

    // L3: out = BN2(C) @ w3 + b3 (fp32 out; BN fold from shadow sums)
    gemm_p<48, 64, 16, 16, 44, 1, false, false, true><<<GB, 256, 0, stream>>>(
        bufC, wt3, biasf3, sum2, ss2, gamma2, beta2, invN, out, nullptr, nullptr);
}

// Round 6
// 234.500 us; speedup vs baseline: 1.0419x; 1.0419x over previous
//
#include <hip/hip_runtime.h>

#define GRIDW 48
#define NNODES 147456
#define NTILES 2304   // NNODES/64
#define GB 512        // persistent GEMM grid
#define NSH 8         // stat shadow copies (XCD-indexed)
#define SHS 128       // shadow stride (floats)

typedef __attribute__((ext_vector_type(8))) short short8;
typedef __attribute__((ext_vector_type(4))) float f32x4;

__device__ inline unsigned short f2bf(float f) {
    union { float f; unsigned u; } v; v.f = f;
    unsigned r = v.u + 0x7FFFu + ((v.u >> 16) & 1u);
    return (unsigned short)(r >> 16);
}
__device__ inline float bf2f(unsigned short h) {
    union { unsigned u; float f; } v; v.u = ((unsigned)h) << 16;
    return v.f;
}
__device__ __forceinline__ f32x4 b2v(uint2 v) {
    f32x4 r;
    r.x = bf2f((unsigned short)(v.x & 0xFFFFu));
    r.y = bf2f((unsigned short)(v.x >> 16));
    r.z = bf2f((unsigned short)(v.y & 0xFFFFu));
    r.w = bf2f((unsigned short)(v.y >> 16));
    return r;
}

// ---------------------------------------------------------------------------
// prep: weights->bf16 [col][KP] (k-contig, zero-padded), padded biases,
// zero stat shadows (re-zeroed every graph replay -> atomic accum safe).
// wt2 is 176 cols: [g2(132) | w2(44)].
// ---------------------------------------------------------------------------
__global__ void prep(const float* __restrict__ w0, const float* __restrict__ b0,
                     const float* __restrict__ w1, const float* __restrict__ b1,
                     const float* __restrict__ g2, const float* __restrict__ w2,
                     const float* __restrict__ b2, const float* __restrict__ w3,
                     const float* __restrict__ b3,
                     unsigned short* __restrict__ wt0, unsigned short* __restrict__ wt1,
                     unsigned short* __restrict__ wt2, unsigned short* __restrict__ wt3,
                     float* __restrict__ biasf0, float* __restrict__ biasf1,
                     float* __restrict__ biasf2, float* __restrict__ biasf3,
                     float* __restrict__ statz) {
    int id = blockIdx.x * 256 + threadIdx.x;
    if (id < 14336) {                         // wt0: 112 cols x 128 k
        int col = id >> 7, k = id & 127;
        wt0[id] = (col < 102) ? f2bf(w0[k * 102 + col]) : (unsigned short)0;
    } else if (id < 24576) {                  // wt1: 80 x 128
        int e = id - 14336; int col = e >> 7, k = e & 127;
        wt1[e] = (col < 73 && k < 102) ? f2bf(w1[k * 73 + col]) : (unsigned short)0;
    } else if (id < 41472) {                  // wt2: 176 x 96 (g2 | w2)
        int e = id - 24576; int col = e / 96, k = e - (e / 96) * 96;
        unsigned short v = 0;
        if (k < 73) v = (col < 132) ? f2bf(g2[k * 132 + col]) : f2bf(w2[k * 44 + (col - 132)]);
        wt2[e] = v;
    } else if (id < 42496) {                  // wt3: 16 x 64
        int e = id - 41472; int col = e >> 6, k = e & 63;
        wt3[e] = (k < 44) ? f2bf(w3[k * 16 + col]) : (unsigned short)0;
    } else if (id < 42608) { int c = id - 42496; biasf0[c] = (c < 102) ? b0[c] : 0.f; }
    else if (id < 42688) { int c = id - 42608; biasf1[c] = (c < 73) ? b1[c] : 0.f; }
    else if (id < 42864) { int c = id - 42688; biasf2[c] = (c < 132) ? 0.f : b2[c - 132]; }
    else if (id < 42880) { int c = id - 42864; biasf3[c] = b3[c]; }
    else if (id < 49024) { statz[id - 42880] = 0.f; }   // 6 x 1024 stat shadows
}

// ---------------------------------------------------------------------------
// Persistent MFMA GEMM: whole-K in LDS, 64-row tiles grid-strided,
// double-buffered A with register prefetch, BN of the previous layer applied
// on the A side during LDS commit. STATS: per-block reduction -> atomicAdd
// into 8 XCD-indexed shadow copies; consumers sum shadows in prologue.
// ---------------------------------------------------------------------------
template<int K, int KP, int MP, int MOUT, int PREVM, int BNSRC,
         bool STATS, bool OUTBF, bool ABF16>
__global__ __launch_bounds__(256) void gemm_p(
    const void* __restrict__ Ain, const unsigned short* __restrict__ WT,
    const float* __restrict__ biasf,
    const float* __restrict__ q0, const float* __restrict__ q1,
    const float* __restrict__ q2, const float* __restrict__ q3,
    float invN, void* __restrict__ Yout,
    float* __restrict__ sumO, float* __restrict__ ssO)
{
    constexpr int KS = KP + 8;
    constexpr int NCF = MP / 16;
    constexpr int UPR = ABF16 ? (K / 8) : (K / 4);
    constexpr int TOT = 64 * UPR;
    constexpr int NLD = (TOT + 255) / 256;
    __shared__ __align__(16) unsigned short As[2][64 * KS];
    __shared__ __align__(16) unsigned short Bs[MP * KS];
    __shared__ float bnA[KP], bnB[KP];

    const int tid = threadIdx.x;
    const int lane = tid & 63, wv = tid >> 6, qd = lane >> 4, lc = lane & 15;

    if (BNSRC == 1) {
        if (tid < KP) {
            float a = 0.f, b = 0.f;
            if (tid < PREVM) {
                float s0 = 0.f, s1 = 0.f;
#pragma unroll
                for (int sh = 0; sh < NSH; ++sh) {
                    s0 += q0[sh * SHS + tid];
                    s1 += q1[sh * SHS + tid];
                }
                float m = s0 * invN;
                float v = s1 * invN - m * m;
                float sc = q2[tid] * rsqrtf(v + 1e-5f);
                a = sc; b = q3[tid] - m * sc;
            }
            bnA[tid] = a; bnB[tid] = b;
        }
    }
    for (int g = tid; g < MP * (KP / 8); g += 256) {
        int col = g / (KP / 8), u = g - col * (KP / 8);
        *(uint4*)&Bs[col * KS + u * 8] = *(const uint4*)&WT[(size_t)col * KP + u * 8];
    }
    if constexpr (KP > K) {
        constexpr int PADU = (KP - K) / 2;
        for (int g = tid; g < 64 * PADU; g += 256) {
            int row = g / PADU, u = g - row * PADU;
            *(unsigned*)&As[0][row * KS + K + u * 2] = 0u;
            *(unsigned*)&As[1][row * KS + K + u * 2] = 0u;
        }
    }

    float bvr[NCF];
#pragma unroll
    for (int cf = 0; cf < NCF; ++cf) bvr[cf] = biasf[cf * 16 + lc];

    float cs[NCF], cq[NCF];
    if (STATS) {
#pragma unroll
        for (int cf = 0; cf < NCF; ++cf) { cs[cf] = 0.f; cq[cf] = 0.f; }
    }

    uint4 pfb[NLD];
    float4 pff[NLD];

    int t = blockIdx.x;
#pragma unroll
    for (int i = 0; i < NLD; ++i) {
        int g = tid + 256 * i;
        if (g < TOT) {
            if constexpr (ABF16)
                pfb[i] = *(const uint4*)((const unsigned short*)Ain + (size_t)t * 64 * K + g * 8);
            else
                pff[i] = *(const float4*)((const float*)Ain + (size_t)t * 64 * K + g * 4);
        }
    }
    __syncthreads();

    int buf = 0;
    for (; t < NTILES; t += GB) {
#pragma unroll
        for (int i = 0; i < NLD; ++i) {
            int g = tid + 256 * i;
            if (g < TOT) {
                int row = g / UPR, u = g - row * UPR;
                if constexpr (ABF16) {
                    uint4 w = pfb[i];
                    if (BNSRC != 0) {
                        unsigned* wp = (unsigned*)&w;
#pragma unroll
                        for (int pp = 0; pp < 4; ++pp) {
                            int kk = u * 8 + 2 * pp;
                            float lo = bf2f((unsigned short)(wp[pp] & 0xFFFFu)) * bnA[kk] + bnB[kk];
                            float hi = bf2f((unsigned short)(wp[pp] >> 16)) * bnA[kk + 1] + bnB[kk + 1];
                            wp[pp] = (unsigned)f2bf(lo) | ((unsigned)f2bf(hi) << 16);
                        }
                    }
                    *(uint4*)&As[buf][row * KS + u * 8] = w;
                } else {
                    float4 v = pff[i];
                    if (BNSRC != 0) {
                        int kk = u * 4;
                        v.x = v.x * bnA[kk] + bnB[kk];
                        v.y = v.y * bnA[kk + 1] + bnB[kk + 1];
                        v.z = v.z * bnA[kk + 2] + bnB[kk + 2];
                        v.w = v.w * bnA[kk + 3] + bnB[kk + 3];
                    }
                    unsigned lo = (unsigned)f2bf(v.x) | ((unsigned)f2bf(v.y) << 16);
                    unsigned hi = (unsigned)f2bf(v.z) | ((unsigned)f2bf(v.w) << 16);
                    *(uint2*)&As[buf][row * KS + u * 4] = make_uint2(lo, hi);
                }
            }
        }
        int t2 = t + GB;
        if (t2 < NTILES) {
#pragma unroll
            for (int i = 0; i < NLD; ++i) {
                int g = tid + 256 * i;
                if (g < TOT) {
                    if constexpr (ABF16)
                        pfb[i] = *(const uint4*)((const unsigned short*)Ain + (size_t)t2 * 64 * K + g * 8);
                    else
                        pff[i] = *(const float4*)((const float*)Ain + (size_t)t2 * 64 * K + g * 4);
                }
            }
        }
        __syncthreads();

        f32x4 acc[NCF];
#pragma unroll
        for (int cf = 0; cf < NCF; ++cf) acc[cf] = (f32x4){0.f, 0.f, 0.f, 0.f};
#pragma unroll
        for (int kt = 0; kt < KP / 32; ++kt) {
            const int kb = kt * 32 + qd * 8;
            short8 a = *(const short8*)&As[buf][(wv * 16 + lc) * KS + kb];
#pragma unroll
            for (int cf = 0; cf < NCF; ++cf) {
                short8 b = *(const short8*)&Bs[(cf * 16 + lc) * KS + kb];
                acc[cf] = __builtin_amdgcn_mfma_f32_16x16x32_bf16(a, b, acc[cf], 0, 0, 0);
            }
        }
#pragma unroll
        for (int cf = 0; cf < NCF; ++cf) {
            const int col = cf * 16 + lc;
            const float bv = bvr[cf];
#pragma unroll
            for (int rr = 0; rr < 4; ++rr) {
                float v = acc[cf][rr] + bv;
                int row = t * 64 + wv * 16 + qd * 4 + rr;
                if (OUTBF) ((unsigned short*)Yout)[(size_t)row * MP + col] = f2bf(v);
                else       ((float*)Yout)[(size_t)row * MP + col] = v;
                if (STATS) { cs[cf] += v; cq[cf] += v * v; }
            }
        }
        buf ^= 1;
    }

    if (STATS) {
        __syncthreads();
        float* red = (float*)As;
        float* redq = red + 4 * MP;
#pragma unroll
        for (int cf = 0; cf < NCF; ++cf) {
            float s = cs[cf], qq = cq[cf];
            s += __shfl_down(s, 32, 64); s += __shfl_down(s, 16, 64);
            qq += __shfl_down(qq, 32, 64); qq += __shfl_down(qq, 16, 64);
            if (lane < 16) {
                red[wv * MP + cf * 16 + lane] = s;
                redq[wv * MP + cf * 16 + lane] = qq;
            }
        }
        __syncthreads();
        if (tid < MOUT) {
            float s = red[tid] + red[MP + tid] + red[2 * MP + tid] + red[3 * MP + tid];
            float qq = redq[tid] + redq[MP + tid] + redq[2 * MP + tid] + redq[3 * MP + tid];
            const int sh = blockIdx.x & (NSH - 1);      // XCD-indexed shadow
            atomicAdd(&sumO[sh * SHS + tid], s);
            atomicAdd(&ssO[sh * SHS + tid], qq);
        }
    }
}

// ---------------------------------------------------------------------------
// Separable GMM stencil (round 15): MLP fix. __launch_bounds__(256,2) lifts
// the default 8-waves/SIMD VGPR cap (~64) that forced load serialization in
// r12-r14 (VGPR stuck at 48-60, ~33K cyc/wave = 48 loads x ~full latency).
// All 45 neighbor uint2 loads + 3 residual loads are issued flat with
// clamped addresses + zero-masked weights (no control flow between loads)
// -> ~48-deep MLP per wave. Border math bit-identical (0*finite = ±0, same
// accumulation order).
// ---------------------------------------------------------------------------
__global__ __launch_bounds__(256, 2) void gmm_stencil(
    const unsigned short* __restrict__ TR, unsigned short* __restrict__ C,
    const float* __restrict__ mu, const float* __restrict__ sigma,
    float* __restrict__ sum2, float* __restrict__ ss2)
{
    __shared__ float gx[3][3], gy[3][3];   // [d][k]
    __shared__ float red[88];
    const int tid = threadIdx.x;
    if (tid < 88) red[tid] = 0.f;
    if (tid < 18) {
        int d = (tid / 3) % 3, k = tid % 3;
        bool isy = tid >= 9;
        float e = 0.5f * (float)(d - 1) + 0.5f;
        float mm = mu[k * 2 + (isy ? 1 : 0)];
        float sg = sigma[k * 2 + (isy ? 1 : 0)];
        float v = expf(-0.5f * (e - mm) * (e - mm) / (1e-15f + sg * sg));
        if (isy) gy[d][k] = v; else gx[d][k] = v;
    }
    __syncthreads();

    // flat uniform mapping, XCD-locality-preserving
    const int xcd = blockIdx.x & 7;
    const int bi  = blockIdx.x >> 3;              // 0..263
    const int b   = xcd * 8 + bi / 33;            // 8 batches per XCD slot
    const unsigned tau = (unsigned)(bi % 33) * 256u + (unsigned)tid;  // 0..8447
    const int og = (int)(tau % 11u);
    const unsigned r1 = tau / 11u;                // 0..767
    const int iy = (int)(r1 % 48u);
    const int x0 = (int)(r1 / 48u) * 3;           // 0..45 step 3
    const int c0 = og * 4;

    // hoist the 18 Gaussian coefficients LDS -> registers (static indices)
    float gxr[3][3], gyr[3][3];
#pragma unroll
    for (int d = 0; d < 3; ++d)
#pragma unroll
        for (int k = 0; k < 3; ++k) { gxr[d][k] = gx[d][k]; gyr[d][k] = gy[d][k]; }

    const int iym = (iy > 0) ? iy - 1 : 0;              // clamped y-neighbors
    const int iyp = (iy < GRIDW - 1) ? iy + 1 : GRIDW - 1;
    const float my0 = (iy > 0) ? 1.f : 0.f;
    const float my2 = (iy < GRIDW - 1) ? 1.f : 0.f;

    // --- flat load phase: one column = 9 unconditional uint2 loads (clamped
    // addr) + 3 validity masks. Named SSA values only.
#define LOADCOL(JX, VM0,VM1,VM2, V00,V01,V02, VP0,VP1,VP2, W0,W1,W2)           \
    float W0, W1, W2;                                                          \
    uint2 VM0, VM1, VM2, V00, V01, V02, VP0, VP1, VP2;                         \
    {                                                                          \
        const int jx_ = (JX);                                                  \
        const bool vx_ = (jx_ >= 0) && (jx_ < GRIDW);                          \
        const int jxc_ = vx_ ? jx_ : 0;                                        \
        const float fx_ = vx_ ? 1.f : 0.f;                                     \
        W0 = fx_ * my0; W1 = fx_; W2 = fx_ * my2;                              \
        const unsigned short* rowp_ = TR + (size_t)(b * 2304 + jxc_ * 48) * 176;\
        const unsigned short* npm_ = rowp_ + (size_t)iym * 176 + c0;           \
        const unsigned short* np0_ = rowp_ + (size_t)iy  * 176 + c0;           \
        const unsigned short* npp_ = rowp_ + (size_t)iyp * 176 + c0;           \
        VM0 = *(const uint2*)(npm_);      VM1 = *(const uint2*)(npm_ + 44);    \
        VM2 = *(const uint2*)(npm_ + 88);                                      \
        V00 = *(const uint2*)(np0_);      V01 = *(const uint2*)(np0_ + 44);    \
        V02 = *(const uint2*)(np0_ + 88);                                      \
        VP0 = *(const uint2*)(npp_);      VP1 = *(const uint2*)(npp_ + 44);    \
        VP2 = *(const uint2*)(npp_ + 88);                                      \
    }

    LOADCOL(x0 - 1, am0, am1, am2, a00, a01, a02, ap0, ap1, ap2, wa0, wa1, wa2)
    LOADCOL(x0,     bm0, bm1, bm2, b00, b01, b02, bp0, bp1, bp2, wb0, wb1, wb2)
    LOADCOL(x0 + 1, cm0, cm1, cm2, c00, c01, c02, cp0, cp1, cp2, wc0, wc1, wc2)
    LOADCOL(x0 + 2, dm0, dm1, dm2, d00, d01, d02, dp0, dp1, dp2, wd0, wd1, wd2)
    LOADCOL(x0 + 3, em0, em1, em2, e00, e01, e02, ep0, ep1, ep2, we0, we1, we2)
#undef LOADCOL

    // residual (root) loads for the 3 output nodes — same flat phase
    const int node0 = b * 2304 + (x0 + 0) * 48 + iy;
    const int node1 = b * 2304 + (x0 + 1) * 48 + iy;
    const int node2 = b * 2304 + (x0 + 2) * 48 + iy;
    uint2 rv0 = *(const uint2*)(TR + (size_t)node0 * 176 + 132 + c0);
    uint2 rv1 = *(const uint2*)(TR + (size_t)node1 * 176 + 132 + c0);
    uint2 rv2 = *(const uint2*)(TR + (size_t)node2 * 176 + 132 + c0);

    // --- combine phase: y-combine each column (same accumulation order as
    // the old ascending-dy loop: ((0+a)+b)+c ).
#define YCOMB(U0, U1, U2, W0, W1, W2, VM0,VM1,VM2, V00,V01,V02, VP0,VP1,VP2)   \
    f32x4 U0 = (W0 * gyr[0][0]) * b2v(VM0);                                    \
    U0 += (W1 * gyr[1][0]) * b2v(V00);                                         \
    U0 += (W2 * gyr[2][0]) * b2v(VP0);                                         \
    f32x4 U1 = (W0 * gyr[0][1]) * b2v(VM1);                                    \
    U1 += (W1 * gyr[1][1]) * b2v(V01);                                         \
    U1 += (W2 * gyr[2][1]) * b2v(VP1);                                         \
    f32x4 U2 = (W0 * gyr[0][2]) * b2v(VM2);                                    \
    U2 += (W1 * gyr[1][2]) * b2v(V02);                                         \
    U2 += (W2 * gyr[2][2]) * b2v(VP2);

    YCOMB(ua0, ua1, ua2, wa0, wa1, wa2, am0,am1,am2, a00,a01,a02, ap0,ap1,ap2)
    YCOMB(ub0, ub1, ub2, wb0, wb1, wb2, bm0,bm1,bm2, b00,b01,b02, bp0,bp1,bp2)
    YCOMB(uc0, uc1, uc2, wc0, wc1, wc2, cm0,cm1,cm2, c00,c01,c02, cp0,cp1,cp2)
    YCOMB(ud0, ud1, ud2, wd0, wd1, wd2, dm0,dm1,dm2, d00,d01,d02, dp0,dp1,dp2)
    YCOMB(ue0, ue1, ue2, we0, we1, we2, em0,em1,em2, e00,e01,e02, ep0,ep1,ep2)
#undef YCOMB

    const int ny = 1 + (iy > 0) + (iy < GRIDW - 1);
    f32x4 s4 = (f32x4){0.f, 0.f, 0.f, 0.f};
    f32x4 q4 = (f32x4){0.f, 0.f, 0.f, 0.f};

#define GOUT(ST, NODE, RV, A0, A1, A2, B0, B1, B2, D0, D1, D2)                 \
    {                                                                          \
        const int ix_ = x0 + (ST);                                             \
        const int nx_ = 1 + (ix_ > 0) + (ix_ < GRIDW - 1);                     \
        const float inv_ = 1.f / (float)(nx_ * ny);                            \
        f32x4 o = (f32x4){0.f, 0.f, 0.f, 0.f};                                 \
        o += gxr[0][0] * A0 + gxr[1][0] * B0 + gxr[2][0] * D0;                 \
        o += gxr[0][1] * A1 + gxr[1][1] * B1 + gxr[2][1] * D1;                 \
        o += gxr[0][2] * A2 + gxr[1][2] * B2 + gxr[2][2] * D2;                 \
        o = o * inv_;                                                          \
        o += b2v(RV);                                                          \
        unsigned lo_ = (unsigned)f2bf(o.x) | ((unsigned)f2bf(o.y) << 16);      \
        unsigned hi_ = (unsigned)f2bf(o.z) | ((unsigned)f2bf(o.w) << 16);      \
        *(uint2*)&C[(size_t)(NODE) * 48 + c0] = make_uint2(lo_, hi_);          \
        if (og == 10)                                                          \
            *(uint2*)&C[(size_t)(NODE) * 48 + 44] = make_uint2(0u, 0u);        \
        s4 += o; q4 += o * o;                                                  \
    }

    GOUT(0, node0, rv0, ua0, ua1, ua2, ub0, ub1, ub2, uc0, uc1, uc2)
    GOUT(1, node1, rv1, ub0, ub1, ub2, uc0, uc1, uc2, ud0, ud1, ud2)
    GOUT(2, node2, rv2, uc0, uc1, uc2, ud0, ud1, ud2, ue0, ue1, ue2)
#undef GOUT

    atomicAdd(&red[c0 + 0], s4.x);
    atomicAdd(&red[c0 + 1], s4.y);
    atomicAdd(&red[c0 + 2], s4.z);
    atomicAdd(&red[c0 + 3], s4.w);
    atomicAdd(&red[44 + c0 + 0], q4.x);
    atomicAdd(&red[44 + c0 + 1], q4.y);
    atomicAdd(&red[44 + c0 + 2], q4.z);
    atomicAdd(&red[44 + c0 + 3], q4.w);
    __syncthreads();
    if (tid < 88) {
        const int sh = blockIdx.x & (NSH - 1);
        if (tid < 44) atomicAdd(&sum2[sh * SHS + tid], red[tid]);
        else          atomicAdd(&ss2[sh * SHS + tid - 44], red[tid]);
    }
}

// ---------------------------------------------------------------------------
extern "C" void kernel_launch(void* const* d_in, const int* in_sizes, int n_in,
                              void* d_out, int out_size, void* d_ws, size_t ws_size,
                              hipStream_t stream) {
    const float* x      = (const float*)d_in[0];
    const float* w0     = (const float*)d_in[3];
    const float* b0     = (const float*)d_in[4];
    const float* gamma0 = (const float*)d_in[5];
    const float* beta0  = (const float*)d_in[6];
    const float* w1     = (const float*)d_in[7];
    const float* b1     = (const float*)d_in[8];
    const float* gamma1 = (const float*)d_in[9];
    const float* beta1  = (const float*)d_in[10];
    const float* w2     = (const float*)d_in[11];
    const float* g2     = (const float*)d_in[12];
    const float* mu2    = (const float*)d_in[13];
    const float* sigma2 = (const float*)d_in[14];
    const float* b2     = (const float*)d_in[15];
    const float* gamma2 = (const float*)d_in[16];
    const float* beta2  = (const float*)d_in[17];
    const float* w3     = (const float*)d_in[18];
    const float* b3     = (const float*)d_in[19];
    float* out = (float*)d_out;

    const int N = NNODES;
    const float invN = 1.0f / (float)N;

    // [0,44N): Y1 bf16 (40N f-eq) then C bf16 48 cols (24N f-eq) — disjoint
    // [44N,132N): Y0 bf16 (56N f-eq) then TR bf16 176 cols (88N f-eq) — disjoint
    const size_t tailOff = (size_t)N * 132;
    size_t need = (tailOff + 300000) * sizeof(float);
    if (ws_size < need) return;

    float* ws = (float*)d_ws;
    unsigned short* bufY1 = (unsigned short*)ws;
    unsigned short* bufC  = (unsigned short*)ws;
    unsigned short* bufY0 = (unsigned short*)(ws + (size_t)N * 44);
    unsigned short* bufTR = bufY0;

    float* tail = ws + tailOff;
    // 6 stat arrays x 8 shadows x 128 stride = 6144 floats
    float* sum0 = tail;                 // 1024
    float* ss0  = tail + 1024;          // 1024
    float* sum1 = tail + 2048;          // 1024
    float* ss1  = tail + 3072;          // 1024
    float* sum2 = tail + 4096;          // 1024
    float* ss2  = tail + 5120;          // 1024
    float* biasf0 = tail + 6144;        // 112
    float* biasf1 = tail + 6256;        // 80
    float* biasf2 = tail + 6336;        // 176
    float* biasf3 = tail + 6512;        // 16
    unsigned short* wt0 = (unsigned short*)(tail + 6528);   // 112*128
    unsigned short* wt1 = wt0 + 14336;                      // 80*128
    unsigned short* wt2 = wt1 + 10240;                      // 176*96
    unsigned short* wt3 = wt2 + 16896;                      // 16*64

    // prep re-zeros the stat shadows each replay (graph-safe).
    prep<<<192, 256, 0, stream>>>(w0, b0, w1, b1, g2, w2, b2, w3, b3,
                                  wt0, wt1, wt2, wt3,
                                  biasf0, biasf1, biasf2, biasf3, tail);

    // L0: Y0 = x @ w0 + b0 (bf16 out, stats -> sum0/ss0 shadows)
    gemm_p<128, 128, 112, 102, 0, 0, true, true, false><<<GB, 256, 0, stream>>>(
        x, wt0, biasf0, nullptr, nullptr, nullptr, nullptr, invN, bufY0, sum0, ss0);

    // L1: Y1 = BN0(Y0) @ w1 + b1 (BN on A-side; stats -> sum1/ss1 shadows)
    gemm_p<112, 128, 80, 73, 102, 1, true, true, true><<<GB, 256, 0, stream>>>(
        bufY0, wt1, biasf1, sum0, ss0, gamma0, beta0, invN, bufY1, sum1, ss1);

    // L2: TR = BN1(Y1) @ [g2 | w2] (+[0|b2]), 176 wide
    gemm_p<80, 96, 176, 176, 73, 1, false, true, true><<<GB, 256, 0, stream>>>(
        bufY1, wt2, biasf2, sum1, ss1, gamma1, beta1, invN, bufTR, nullptr, nullptr);

    // separable stencil: C(bf16,48) = r + agg(t)/deg ; stats -> sum2/ss2 shadows
    gmm_stencil<<<2112, 256, 0, stream>>>(bufTR, bufC, mu2, sigma2, sum2, ss2);

    // L3: out = BN2(C) @ w3 + b3 (fp32 out; BN fold from shadow sums)
    gemm_p<48, 64, 16, 16, 44, 1, false, false, true><<<GB, 256, 0, stream>>>(
        bufC, wt3, biasf3, sum2, ss2, gamma2, beta2, invN, out, nullptr, nullptr);
}